// Round 7
// baseline (286.185 us; speedup 1.0000x reference)
//
#include <hip/hip_runtime.h>
#include <stdint.h>

#define H100 100
#define T64  64
#define NB   128
#define DLAG 10

// ---- workspace layout (uint32 offsets) ----
#define OFF_HH0 0          // [2][300][50] hh0 row-pair-packed
#define OFF_IH1 30000      // [2][300][50]
#define OFF_HH1 60000      // [2][300][50]
#define OFF_CTX 90000      // [100][100]  ctx row-pair-packed (o-major)
#define OFF_AWC 100000     // [50] attn_w[0][100:200] pairs
#define OFF_OW  100050     // [2][50] out_w halves pairs
#define OFF_P   100152     // float [2][128][64] partial readouts

typedef _Float16 half2_t __attribute__((ext_vector_type(2)));
typedef __fp16   pk16x2  __attribute__((ext_vector_type(2)));

__device__ __forceinline__ float fdot2u(uint32_t a, uint32_t b, float c) {
#if __has_builtin(__builtin_amdgcn_fdot2)
    return __builtin_amdgcn_fdot2(__builtin_bit_cast(half2_t, a),
                                  __builtin_bit_cast(half2_t, b), c, false);
#else
    half2_t ha = __builtin_bit_cast(half2_t, a), hb = __builtin_bit_cast(half2_t, b);
    return c + (float)ha[0]*(float)hb[0] + (float)ha[1]*(float)hb[1];
#endif
}
__device__ __forceinline__ uint32_t pkrtz(float a, float b) {
    pk16x2 h = __builtin_amdgcn_cvt_pkrtz(a, b);
    return __builtin_bit_cast(uint32_t, h);
}
__device__ __forceinline__ uint32_t pk_rn(float a, float b) {
    half2_t h; h[0] = (_Float16)a; h[1] = (_Float16)b;
    return __builtin_bit_cast(uint32_t, h);
}
__device__ __forceinline__ float lo16(uint32_t u){ return (float)__builtin_bit_cast(half2_t,u)[0]; }
__device__ __forceinline__ float hi16(uint32_t u){ return (float)__builtin_bit_cast(half2_t,u)[1]; }
__device__ __forceinline__ float sigm(float x){ return 1.f/(1.f+__expf(-x)); }
__device__ __forceinline__ float tanhfast(float x){ return 1.f - 2.f/(1.f+__expf(2.f*x)); }
__device__ __forceinline__ float gru_el(float pr, float pz, float gin, float ghn, float hp) {
    float r = sigm(pr), z = sigm(pz);
    float n = tanhfast(gin + r*ghn);
    return (1.f - z)*n + z*hp;
}
__device__ __forceinline__ float wsum(float v){
    #pragma unroll
    for (int off = 32; off; off >>= 1) v += __shfl_xor(v, off);
    return v;
}
__device__ __forceinline__ float wmax(float v){
    #pragma unroll
    for (int off = 32; off; off >>= 1) v = fmaxf(v, __shfl_xor(v, off));
    return v;
}
__device__ __forceinline__ uint32_t rlane(uint32_t v, int lane){
    return (uint32_t)__builtin_amdgcn_readlane((int)v, lane);
}

struct SMem {
    alignas(16) uint32_t cache_t[2][50][66];  // transposed hidden cache, pad 66
    alignas(16) float grz1[200];
    alignas(16) float gin1[100];
    alignas(16) float ghn1[100];
    alignas(16) float grz2[200];
    alignas(16) float gin2[100];
    alignas(16) float ghn2[100];
    alignas(16) float sv[2][64];
    alignas(16) float atile[2][64];
    alignas(16) uint32_t cpkq[2][64];         // attention context, f16 pairs
    alignas(16) float hmix0[104];
    alignas(16) float hmix1[104];
    alignas(16) float x[192];
};

// ---------------- prep: pack weights to f16 pairs ----------------
__global__ void prep_pack(const float* __restrict__ w1hh0, const float* __restrict__ w2hh0,
                          const float* __restrict__ w1ih1, const float* __restrict__ w2ih1,
                          const float* __restrict__ w1hh1, const float* __restrict__ w2hh1,
                          const float* __restrict__ attw,  const float* __restrict__ ctxw,
                          const float* __restrict__ outw,  uint32_t* __restrict__ ws) {
    int g = blockIdx.x*blockDim.x + threadIdx.x;
    if (g < 30000) {
        int br = g/15000, idx = g%15000;
        int j = idx/50, kp = idx%50;
        const float* w = br ? w2hh0 : w1hh0;
        ws[OFF_HH0 + g] = pk_rn(w[j*H100+2*kp], w[j*H100+2*kp+1]);
    } else if (g < 60000) {
        int t2 = g-30000; int br = t2/15000, idx = t2%15000;
        int j = idx/50, kp = idx%50;
        const float* w = br ? w2ih1 : w1ih1;
        ws[OFF_IH1 + t2] = pk_rn(w[j*H100+2*kp], w[j*H100+2*kp+1]);
    } else if (g < 90000) {
        int t2 = g-60000; int br = t2/15000, idx = t2%15000;
        int j = idx/50, kp = idx%50;
        const float* w = br ? w2hh1 : w1hh1;
        ws[OFF_HH1 + t2] = pk_rn(w[j*H100+2*kp], w[j*H100+2*kp+1]);
    } else if (g < 100000) {
        int idx = g-90000; int o = idx/100, kp = idx%100;
        ws[OFF_CTX + idx] = pk_rn(ctxw[o*200+2*kp], ctxw[o*200+2*kp+1]);
    } else if (g < 100050) {
        int i2 = g-100000;
        ws[OFF_AWC + i2] = pk_rn(attw[100+2*i2], attw[101+2*i2]);
    } else if (g < 100150) {
        int t2 = g-100050; int br = t2/50, i2 = t2%50;
        ws[OFF_OW + t2] = pk_rn(outw[br*H100+2*i2], outw[br*H100+2*i2+1]);
    }
}

// ---------------- main: one block per (branch, batch) chain ----------------
__global__ __launch_bounds__(512, 1)
void gru_seq(const float* __restrict__ recv,
             const float* __restrict__ ih0_1, const float* __restrict__ bih0_1,
             const float* __restrict__ bhh0_1, const float* __restrict__ bih1_1,
             const float* __restrict__ bhh1_1,
             const float* __restrict__ ih0_2, const float* __restrict__ bih0_2,
             const float* __restrict__ bhh0_2, const float* __restrict__ bih1_2,
             const float* __restrict__ bhh1_2,
             const float* __restrict__ ctxb,
             uint32_t* __restrict__ ws) {
    __shared__ SMem S;
    const int tid = threadIdx.x;
    const int w   = tid >> 6;
    const int la  = tid & 63;
    const int br  = blockIdx.x >> 7;
    const int b   = blockIdx.x & 127;

    const float* ih0 = br ? ih0_2  : ih0_1;
    const float* bi0 = br ? bih0_2 : bih0_1;
    const float* bh0 = br ? bhh0_2 : bhh0_1;
    const float* bi1 = br ? bih1_2 : bih1_1;
    const float* bh1 = br ? bhh1_2 : bhh1_1;

    // staging + init
    for (int i = tid; i < 192; i += 512) S.x[i] = recv[b*192 + i];
    for (int i = tid; i < 2*50*66; i += 512) ((uint32_t*)S.cache_t)[i] = 0u;
    if (tid < 128) S.sv[tid>>6][tid&63] = 0.f;

    // role-overlaid register file
    uint32_t wreg[150];
    float fb0=0.f, fb1=0.f, fb2=0.f, fb3=0.f;
    float rix0=0.f, rix1=0.f, rix2=0.f;
    if (tid < 300) {
        const uint32_t* p0 = ws + OFF_HH0 + br*15000 + tid*50;
        const uint32_t* p1 = ws + OFF_HH1 + br*15000 + tid*50;
        const uint32_t* p2 = ws + OFF_IH1 + br*15000 + tid*50;
        #pragma unroll
        for (int k = 0; k < 50; ++k) { wreg[k] = p0[k]; wreg[50+k] = p1[k]; wreg[100+k] = p2[k]; }
        fb0 = bi0[tid]; fb1 = bh0[tid]; fb2 = bi1[tid]; fb3 = bh1[tid];
        rix0 = ih0[tid*3]; rix1 = ih0[tid*3+1]; rix2 = ih0[tid*3+2];
    } else if (tid < 400) {
        const int o = tid - 300;
        const uint32_t* pc = ws + OFF_CTX + o*100;
        #pragma unroll
        for (int k = 0; k < 100; ++k) wreg[k] = pc[k];
        fb0 = ctxb[o];
    }
    uint32_t rawc = 0u, rowp = 0u;
    if (w == 0 && la < 50) rawc = ws[OFF_AWC + la];
    if (w == 7 && la < 50) rowp = ws[OFF_OW + br*50 + la];
    float* p_out = (float*)(ws + OFF_P);

    uint32_t hn0p = 0u, hn1p = 0u, h0cp = 0u, h1cp = 0u;
    float gh1save = 0.f;
    __syncthreads();

    for (int t = 0; t < T64; ++t) {
        // ================= P1: carry-combine (all) | gates (w0-4) | attn (w5,6) | readout (w7) =====
        if (la < 50) {
            if (t == 0)      { h0cp = 0u;   h1cp = 0u;   }
            else if (t == 1) { h0cp = hn0p; h1cp = hn1p; }
            else {
                float2 a0 = *(const float2*)&S.hmix0[2*la];
                float2 a1 = *(const float2*)&S.hmix1[2*la];
                h0cp = pkrtz(a0.x, a0.y);
                h1cp = pkrtz(a1.x, a1.y);
            }
        }
        if (tid < 300) {
            float x0 = S.x[3*t], x1 = S.x[3*t+1], x2 = S.x[3*t+2];
            float accI = fb0 + rix0*x0 + rix1*x1 + rix2*x2;
            float a0a = 0.f, a0b = 0.f;
            #pragma unroll
            for (int k = 0; k < 50; k += 2) {
                a0a = fdot2u(wreg[k],   rlane(h0cp, k),   a0a);
                a0b = fdot2u(wreg[k+1], rlane(h0cp, k+1), a0b);
            }
            float a1a = 0.f, a1b = 0.f;
            #pragma unroll
            for (int k = 0; k < 50; k += 2) {
                a1a = fdot2u(wreg[50+k],   rlane(h1cp, k),   a1a);
                a1b = fdot2u(wreg[50+k+1], rlane(h1cp, k+1), a1b);
            }
            float acc0 = fb1 + a0a + a0b;
            gh1save = fb3 + a1a + a1b;
            if (tid < 200) S.grz1[tid] = accI + acc0;
            else { S.gin1[tid-200] = accI; S.ghn1[tid-200] = acc0; }
        } else if (w == 5 || w == 6) {
            const int l = w - 5;
            const int m = (t > 1) ? t : 1;
            float sval = S.sv[l][la];
            float sv2  = (la < m) ? sval : -3e38f;
            float mx   = wmax(sv2);
            float p    = (la < m) ? __expf(sv2 - mx) : 0.f;
            float ssum = wsum(p);
            S.atile[l][la] = p;
            if (la < 50) {
                float c0 = 0.f, c1 = 0.f;
                const uint32_t* crow = &S.cache_t[l][la][0];
                // Full compile-time unroll: slots >= m contribute 0 (atile=0 there,
                // cache slots >= t still zero). Static trip count lets all 64
                // ds_reads pipeline instead of serializing at LDS latency per
                // iteration (R6 post-mortem: runtime-bound loop was the critical
                // path, ~120cy x m/2 per step).
                #pragma unroll
                for (int tp = 0; tp < 32; ++tp) {
                    float2 ap = *(const float2*)&S.atile[l][2*tp];
                    uint2  cp = *(const uint2*)&crow[2*tp];
                    c0 += ap.x*lo16(cp.x) + ap.y*lo16(cp.y);
                    c1 += ap.x*hi16(cp.x) + ap.y*hi16(cp.y);
                }
                float inv = 1.f/ssum;
                S.cpkq[l][la] = pkrtz(c0*inv, c1*inv);
            }
        } else if (w == 7 && t > 0) {
            float v = (la < 50) ? fdot2u(rowp, hn1p, 0.f) : 0.f;
            v = wsum(v);
            if (la == 0) p_out[br*8192 + b*64 + (t-1)] = v;
        }
        __syncthreads();
        // ================= P2: hn0 (all waves) ; s0/cache0 (w0) ; gi1 (w0-4) =====
        if (la < 50) {
            float2 pr = *(const float2*)&S.grz1[2*la];
            float2 pz = *(const float2*)&S.grz1[100+2*la];
            float2 gi = *(const float2*)&S.gin1[2*la];
            float2 gh = *(const float2*)&S.ghn1[2*la];
            float h0 = gru_el(pr.x, pz.x, gi.x, gh.x, lo16(h0cp));
            float h1 = gru_el(pr.y, pz.y, gi.y, gh.y, hi16(h0cp));
            hn0p = pkrtz(h0, h1);
        }
        if (w == 0) {
            float v = (la < 50) ? fdot2u(rawc, hn0p, 0.f) : 0.f;
            v = wsum(v);
            if (la == 0) S.sv[0][t] = v;
            if (la < 50) S.cache_t[0][la][t] = hn0p;
        }
        if (tid < 300) {
            float ga = 0.f, gb = 0.f;
            #pragma unroll
            for (int k = 0; k < 50; k += 2) {
                ga = fdot2u(wreg[100+k],   rlane(hn0p, k),   ga);
                gb = fdot2u(wreg[100+k+1], rlane(hn0p, k+1), gb);
            }
            float gi1 = fb2 + ga + gb;
            if (tid < 200) S.grz2[tid] = gi1 + gh1save;
            else { S.gin2[tid-200] = gi1; S.ghn2[tid-200] = gh1save; }
        }
        __syncthreads();
        // ================= P3: hn1 (all) ; s1/cache1 (w0) ; ctx-mix (tid 300-399) =====
        if (la < 50) {
            float2 pr = *(const float2*)&S.grz2[2*la];
            float2 pz = *(const float2*)&S.grz2[100+2*la];
            float2 gi = *(const float2*)&S.gin2[2*la];
            float2 gh = *(const float2*)&S.ghn2[2*la];
            float h0 = gru_el(pr.x, pz.x, gi.x, gh.x, lo16(h1cp));
            float h1 = gru_el(pr.y, pz.y, gi.y, gh.y, hi16(h1cp));
            hn1p = pkrtz(h0, h1);
        }
        if (w == 0) {
            float v = (la < 50) ? fdot2u(rawc, hn1p, 0.f) : 0.f;
            v = wsum(v);
            if (la == 0) S.sv[1][t] = v;
            if (la < 50) S.cache_t[1][la][t] = hn1p;
        }
        if (tid >= 300 && tid < 400) {
            const int o = tid - 300;
            float p0 = fb0, p1 = fb0;
            #pragma unroll
            for (int kb = 0; kb < 13; ++kb) {
                uint4 v0 = *(const uint4*)&S.cpkq[0][kb*4];
                uint4 v1 = *(const uint4*)&S.cpkq[1][kb*4];
                #pragma unroll
                for (int i = 0; i < 4; ++i) {
                    const int k = kb*4 + i;
                    if (k < 50) {
                        uint32_t e0 = (i==0)?v0.x:(i==1)?v0.y:(i==2)?v0.z:v0.w;
                        uint32_t e1 = (i==0)?v1.x:(i==1)?v1.y:(i==2)?v1.z:v1.w;
                        p0 = fdot2u(wreg[k], e0, p0);
                        p1 = fdot2u(wreg[k], e1, p1);
                    }
                }
            }
            #pragma unroll
            for (int k = 0; k < 50; ++k) {
                p0 = fdot2u(wreg[50+k], rlane(hn0p, k), p0);
                p1 = fdot2u(wreg[50+k], rlane(hn1p, k), p1);
            }
            S.hmix0[o] = p0; S.hmix1[o] = p1;
        }
        __syncthreads();
    }
    // epilogue: readout for t = 63
    if (w == 7) {
        float v = (la < 50) ? fdot2u(rowp, hn1p, 0.f) : 0.f;
        v = wsum(v);
        if (la == 0) p_out[br*8192 + b*64 + 63] = v;
    }
}

// ---------------- final: pair partials across branches, sigmoid ----------------
__global__ void fin_out(const uint32_t* __restrict__ ws, const float* __restrict__ outb,
                        float* __restrict__ out) {
    int i = blockIdx.x*blockDim.x + threadIdx.x;
    if (i >= NB*T64) return;
    int b = i >> 6, t = i & 63;
    const float* p = (const float*)(ws + OFF_P);
    int t2 = t + DLAG; if (t2 > T64-1) t2 = T64-1;
    float logit = p[0*8192 + b*64 + t] + p[1*8192 + b*64 + t2] + outb[0];
    out[i] = 1.f/(1.f+__expf(-logit));
}

extern "C" void kernel_launch(void* const* d_in, const int* in_sizes, int n_in,
                              void* d_out, int out_size, void* d_ws, size_t ws_size,
                              hipStream_t stream) {
    const float* recv   = (const float*)d_in[0];
    const float* w1ih0  = (const float*)d_in[1];
    const float* w1hh0  = (const float*)d_in[2];
    const float* w1bih0 = (const float*)d_in[3];
    const float* w1bhh0 = (const float*)d_in[4];
    const float* w1ih1  = (const float*)d_in[5];
    const float* w1hh1  = (const float*)d_in[6];
    const float* w1bih1 = (const float*)d_in[7];
    const float* w1bhh1 = (const float*)d_in[8];
    const float* w2ih0  = (const float*)d_in[9];
    const float* w2hh0  = (const float*)d_in[10];
    const float* w2bih0 = (const float*)d_in[11];
    const float* w2bhh0 = (const float*)d_in[12];
    const float* w2ih1  = (const float*)d_in[13];
    const float* w2hh1  = (const float*)d_in[14];
    const float* w2bih1 = (const float*)d_in[15];
    const float* w2bhh1 = (const float*)d_in[16];
    const float* attw   = (const float*)d_in[17];
    const float* ctxw   = (const float*)d_in[19];
    const float* ctxb   = (const float*)d_in[20];
    const float* outw   = (const float*)d_in[21];
    const float* outb   = (const float*)d_in[22];
    uint32_t* ws = (uint32_t*)d_ws;
    float* out = (float*)d_out;

    prep_pack<<<(100150 + 255)/256, 256, 0, stream>>>(
        w1hh0, w2hh0, w1ih1, w2ih1, w1hh1, w2hh1, attw, ctxw, outw, ws);

    gru_seq<<<256, 512, 0, stream>>>(
        recv,
        w1ih0, w1bih0, w1bhh0, w1bih1, w1bhh1,
        w2ih0, w2bih0, w2bhh0, w2bih1, w2bhh1,
        ctxb, ws);

    fin_out<<<(NB*T64 + 255)/256, 256, 0, stream>>>(ws, outb, out);
}

// Round 8
// 240.582 us; speedup vs baseline: 1.1896x; 1.1896x over previous
//
#include <hip/hip_runtime.h>
#include <stdint.h>

#define H100 100
#define T64  64
#define NB   128
#define DLAG 10

// ---- workspace layout (uint32 offsets) ----
#define OFF_HH0 0          // [2][300][50] hh0 row-pair-packed
#define OFF_IH1 30000      // [2][300][50]
#define OFF_HH1 60000      // [2][300][50]
#define OFF_CTX 90000      // [100][100]  ctx row-pair-packed (o-major)
#define OFF_AWC 100000     // [50] attn_w[0][100:200] pairs
#define OFF_OW  100050     // [2][50] out_w halves pairs
#define OFF_P   100152     // float [2][128][64] partial readouts

typedef _Float16 half2_t __attribute__((ext_vector_type(2)));
typedef __fp16   pk16x2  __attribute__((ext_vector_type(2)));

__device__ __forceinline__ float fdot2u(uint32_t a, uint32_t b, float c) {
#if __has_builtin(__builtin_amdgcn_fdot2)
    return __builtin_amdgcn_fdot2(__builtin_bit_cast(half2_t, a),
                                  __builtin_bit_cast(half2_t, b), c, false);
#else
    half2_t ha = __builtin_bit_cast(half2_t, a), hb = __builtin_bit_cast(half2_t, b);
    return c + (float)ha[0]*(float)hb[0] + (float)ha[1]*(float)hb[1];
#endif
}
__device__ __forceinline__ uint32_t pkrtz(float a, float b) {
    pk16x2 h = __builtin_amdgcn_cvt_pkrtz(a, b);
    return __builtin_bit_cast(uint32_t, h);
}
__device__ __forceinline__ uint32_t pk_rn(float a, float b) {
    half2_t h; h[0] = (_Float16)a; h[1] = (_Float16)b;
    return __builtin_bit_cast(uint32_t, h);
}
__device__ __forceinline__ float lo16(uint32_t u){ return (float)__builtin_bit_cast(half2_t,u)[0]; }
__device__ __forceinline__ float hi16(uint32_t u){ return (float)__builtin_bit_cast(half2_t,u)[1]; }
__device__ __forceinline__ float sigm(float x){ return 1.f/(1.f+__expf(-x)); }
__device__ __forceinline__ float tanhfast(float x){ return 1.f - 2.f/(1.f+__expf(2.f*x)); }
__device__ __forceinline__ float gru_el(float pr, float pz, float gin, float ghn, float hp) {
    float r = sigm(pr), z = sigm(pz);
    float n = tanhfast(gin + r*ghn);
    return (1.f - z)*n + z*hp;
}
__device__ __forceinline__ float wsum(float v){
    #pragma unroll
    for (int off = 32; off; off >>= 1) v += __shfl_xor(v, off);
    return v;
}
__device__ __forceinline__ float wmax(float v){
    #pragma unroll
    for (int off = 32; off; off >>= 1) v = fmaxf(v, __shfl_xor(v, off));
    return v;
}
__device__ __forceinline__ uint32_t rlane(uint32_t v, int lane){
    return (uint32_t)__builtin_amdgcn_readlane((int)v, lane);
}

struct SMem {
    alignas(16) uint32_t cache_t[2][50][66];  // transposed hidden cache, pad 66
    alignas(16) float grz1[200];
    alignas(16) float gin1[100];
    alignas(16) float ghn1[100];
    alignas(16) float grz2[200];
    alignas(16) float gin2[100];
    alignas(16) float ghn2[100];
    alignas(16) float sv[2][64];
    alignas(16) float atile[2][64];
    alignas(16) uint32_t cpkq[2][64];         // attention context, f16 pairs
    alignas(16) float hmix0[104];
    alignas(16) float hmix1[104];
    alignas(16) float x[192];
};

// ---------------- prep: pack weights to f16 pairs ----------------
__global__ void prep_pack(const float* __restrict__ w1hh0, const float* __restrict__ w2hh0,
                          const float* __restrict__ w1ih1, const float* __restrict__ w2ih1,
                          const float* __restrict__ w1hh1, const float* __restrict__ w2hh1,
                          const float* __restrict__ attw,  const float* __restrict__ ctxw,
                          const float* __restrict__ outw,  uint32_t* __restrict__ ws) {
    int g = blockIdx.x*blockDim.x + threadIdx.x;
    if (g < 30000) {
        int br = g/15000, idx = g%15000;
        int j = idx/50, kp = idx%50;
        const float* w = br ? w2hh0 : w1hh0;
        ws[OFF_HH0 + g] = pk_rn(w[j*H100+2*kp], w[j*H100+2*kp+1]);
    } else if (g < 60000) {
        int t2 = g-30000; int br = t2/15000, idx = t2%15000;
        int j = idx/50, kp = idx%50;
        const float* w = br ? w2ih1 : w1ih1;
        ws[OFF_IH1 + t2] = pk_rn(w[j*H100+2*kp], w[j*H100+2*kp+1]);
    } else if (g < 90000) {
        int t2 = g-60000; int br = t2/15000, idx = t2%15000;
        int j = idx/50, kp = idx%50;
        const float* w = br ? w2hh1 : w1hh1;
        ws[OFF_HH1 + t2] = pk_rn(w[j*H100+2*kp], w[j*H100+2*kp+1]);
    } else if (g < 100000) {
        int idx = g-90000; int o = idx/100, kp = idx%100;
        ws[OFF_CTX + idx] = pk_rn(ctxw[o*200+2*kp], ctxw[o*200+2*kp+1]);
    } else if (g < 100050) {
        int i2 = g-100000;
        ws[OFF_AWC + i2] = pk_rn(attw[100+2*i2], attw[101+2*i2]);
    } else if (g < 100150) {
        int t2 = g-100050; int br = t2/50, i2 = t2%50;
        ws[OFF_OW + t2] = pk_rn(outw[br*H100+2*i2], outw[br*H100+2*i2+1]);
    }
}

// ---------------- main: one block per (branch, batch) chain ----------------
__global__ __launch_bounds__(512, 1)
void gru_seq(const float* __restrict__ recv,
             const float* __restrict__ ih0_1, const float* __restrict__ bih0_1,
             const float* __restrict__ bhh0_1, const float* __restrict__ bih1_1,
             const float* __restrict__ bhh1_1,
             const float* __restrict__ ih0_2, const float* __restrict__ bih0_2,
             const float* __restrict__ bhh0_2, const float* __restrict__ bih1_2,
             const float* __restrict__ bhh1_2,
             const float* __restrict__ ctxb,
             uint32_t* __restrict__ ws) {
    __shared__ SMem S;
    const int tid = threadIdx.x;
    const int w   = tid >> 6;
    const int la  = tid & 63;
    const int br  = blockIdx.x >> 7;
    const int b   = blockIdx.x & 127;

    const float* ih0 = br ? ih0_2  : ih0_1;
    const float* bi0 = br ? bih0_2 : bih0_1;
    const float* bh0 = br ? bhh0_2 : bhh0_1;
    const float* bi1 = br ? bih1_2 : bih1_1;
    const float* bh1 = br ? bhh1_2 : bhh1_1;

    // staging + init
    for (int i = tid; i < 192; i += 512) S.x[i] = recv[b*192 + i];
    for (int i = tid; i < 2*50*66; i += 512) ((uint32_t*)S.cache_t)[i] = 0u;
    if (tid < 128) S.sv[tid>>6][tid&63] = 0.f;

    // role-overlaid register file: gates(tid<300): wA=hh0 wB=hh1 wC=ih1 rows;
    // ctx(300-399): wA=ctx c-half, wB=ctx hn-half.
    uint32_t wA[50], wB[50], wC[50];
    float fb0=0.f, fb1=0.f, fb2=0.f, fb3=0.f;
    float rix0=0.f, rix1=0.f, rix2=0.f;
    if (tid < 300) {
        const uint32_t* p0 = ws + OFF_HH0 + br*15000 + tid*50;
        const uint32_t* p1 = ws + OFF_HH1 + br*15000 + tid*50;
        const uint32_t* p2 = ws + OFF_IH1 + br*15000 + tid*50;
        #pragma unroll
        for (int k = 0; k < 50; ++k) { wA[k] = p0[k]; wB[k] = p1[k]; wC[k] = p2[k]; }
        fb0 = bi0[tid]; fb1 = bh0[tid]; fb2 = bi1[tid]; fb3 = bh1[tid];
        rix0 = ih0[tid*3]; rix1 = ih0[tid*3+1]; rix2 = ih0[tid*3+2];
    } else if (tid < 400) {
        const int o = tid - 300;
        const uint32_t* pc = ws + OFF_CTX + o*100;
        #pragma unroll
        for (int k = 0; k < 50; ++k) { wA[k] = pc[k]; wB[k] = pc[50+k]; }
        fb0 = ctxb[o];
    }
    uint32_t rawc = 0u, rowp = 0u;
    if (w == 0 && la < 50) rawc = ws[OFF_AWC + la];
    if (w == 7 && la < 50) rowp = ws[OFF_OW + br*50 + la];
    float* p_out = (float*)(ws + OFF_P);

    uint32_t hn0p = 0u, hn1p = 0u, h0cp = 0u, h1cp = 0u;
    float gh1save = 0.f;
    __syncthreads();

    for (int t = 0; t < T64; ++t) {
        // ===== P1: carry-combine (all) | gates 8-stream (tid<300) | attn (w5,6) | readout (w7) =====
        if (la < 50) {
            if (t == 0)      { h0cp = 0u;   h1cp = 0u;   }
            else if (t == 1) { h0cp = hn0p; h1cp = hn1p; }
            else {
                float2 a0 = *(const float2*)&S.hmix0[2*la];
                float2 a1 = *(const float2*)&S.hmix1[2*la];
                h0cp = pkrtz(a0.x, a0.y);
                h1cp = pkrtz(a1.x, a1.y);
            }
        }
        if (tid < 300) {
            float x0 = S.x[3*t], x1 = S.x[3*t+1], x2 = S.x[3*t+2];
            float accI = fb0 + rix0*x0 + rix1*x1 + rix2*x2;
            // 8 independent chains (4 hh0 + 4 hh1), readlanes hoisted in groups
            float a0=0.f,a1=0.f,a2=0.f,a3=0.f, b0=0.f,b1=0.f,b2=0.f,b3=0.f;
            #pragma unroll
            for (int k = 0; k < 48; k += 4) {
                uint32_t h0a=rlane(h0cp,k), h0b=rlane(h0cp,k+1), h0c=rlane(h0cp,k+2), h0d=rlane(h0cp,k+3);
                uint32_t h1a=rlane(h1cp,k), h1b=rlane(h1cp,k+1), h1c=rlane(h1cp,k+2), h1d=rlane(h1cp,k+3);
                a0 = fdot2u(wA[k],   h0a, a0);
                b0 = fdot2u(wB[k],   h1a, b0);
                a1 = fdot2u(wA[k+1], h0b, a1);
                b1 = fdot2u(wB[k+1], h1b, b1);
                a2 = fdot2u(wA[k+2], h0c, a2);
                b2 = fdot2u(wB[k+2], h1c, b2);
                a3 = fdot2u(wA[k+3], h0d, a3);
                b3 = fdot2u(wB[k+3], h1d, b3);
            }
            {
                uint32_t h0a=rlane(h0cp,48), h0b=rlane(h0cp,49);
                uint32_t h1a=rlane(h1cp,48), h1b=rlane(h1cp,49);
                a0 = fdot2u(wA[48], h0a, a0);
                b0 = fdot2u(wB[48], h1a, b0);
                a1 = fdot2u(wA[49], h0b, a1);
                b1 = fdot2u(wB[49], h1b, b1);
            }
            float acc0 = fb1 + ((a0+a1)+(a2+a3));
            gh1save    = fb3 + ((b0+b1)+(b2+b3));
            if (tid < 200) S.grz1[tid] = accI + acc0;
            else { S.gin1[tid-200] = accI; S.ghn1[tid-200] = acc0; }
        } else if (w == 5 || w == 6) {
            const int l = w - 5;
            const int m = (t > 1) ? t : 1;
            float sval = S.sv[l][la];
            float sv2  = (la < m) ? sval : -3e38f;
            float mx   = wmax(sv2);
            float p    = (la < m) ? __expf(sv2 - mx) : 0.f;
            float ssum = wsum(p);
            S.atile[l][la] = p;
            if (la < 50) {
                float c0 = 0.f, c1 = 0.f;
                const uint32_t* crow = &S.cache_t[l][la][0];
                const int np = (m + 1) >> 1;
                for (int tp = 0; tp < np; ++tp) {
                    float2 ap = *(const float2*)&S.atile[l][2*tp];
                    uint2  cp = *(const uint2*)&crow[2*tp];
                    c0 += ap.x*lo16(cp.x) + ap.y*lo16(cp.y);
                    c1 += ap.x*hi16(cp.x) + ap.y*hi16(cp.y);
                }
                float inv = 1.f/ssum;
                S.cpkq[l][la] = pkrtz(c0*inv, c1*inv);
            }
        } else if (w == 7 && t > 0) {
            float v = (la < 50) ? fdot2u(rowp, hn1p, 0.f) : 0.f;
            v = wsum(v);
            if (la == 0) p_out[br*8192 + b*64 + (t-1)] = v;
        }
        __syncthreads();
        // ===== P2: hn0 (all waves) ; s0/cache0 (w0) ; gi1 4-stream (tid<300) =====
        if (la < 50) {
            float2 pr = *(const float2*)&S.grz1[2*la];
            float2 pz = *(const float2*)&S.grz1[100+2*la];
            float2 gi = *(const float2*)&S.gin1[2*la];
            float2 gh = *(const float2*)&S.ghn1[2*la];
            float h0 = gru_el(pr.x, pz.x, gi.x, gh.x, lo16(h0cp));
            float h1 = gru_el(pr.y, pz.y, gi.y, gh.y, hi16(h0cp));
            hn0p = pkrtz(h0, h1);
        }
        if (w == 0) {
            float v = (la < 50) ? fdot2u(rawc, hn0p, 0.f) : 0.f;
            v = wsum(v);
            if (la == 0) S.sv[0][t] = v;
            if (la < 50) S.cache_t[0][la][t] = hn0p;
        }
        if (tid < 300) {
            float g0=0.f,g1=0.f,g2=0.f,g3=0.f;
            #pragma unroll
            for (int k = 0; k < 48; k += 4) {
                uint32_t ha=rlane(hn0p,k), hb=rlane(hn0p,k+1), hc=rlane(hn0p,k+2), hd=rlane(hn0p,k+3);
                g0 = fdot2u(wC[k],   ha, g0);
                g1 = fdot2u(wC[k+1], hb, g1);
                g2 = fdot2u(wC[k+2], hc, g2);
                g3 = fdot2u(wC[k+3], hd, g3);
            }
            {
                uint32_t ha=rlane(hn0p,48), hb=rlane(hn0p,49);
                g0 = fdot2u(wC[48], ha, g0);
                g1 = fdot2u(wC[49], hb, g1);
            }
            float gi1 = fb2 + ((g0+g1)+(g2+g3));
            if (tid < 200) S.grz2[tid] = gi1 + gh1save;
            else { S.gin2[tid-200] = gi1; S.ghn2[tid-200] = gh1save; }
        }
        __syncthreads();
        // ===== P3: hn1 (all) ; s1/cache1 (w0) ; ctx-mix 4+4-stream (tid 300-399) =====
        if (la < 50) {
            float2 pr = *(const float2*)&S.grz2[2*la];
            float2 pz = *(const float2*)&S.grz2[100+2*la];
            float2 gi = *(const float2*)&S.gin2[2*la];
            float2 gh = *(const float2*)&S.ghn2[2*la];
            float h0 = gru_el(pr.x, pz.x, gi.x, gh.x, lo16(h1cp));
            float h1 = gru_el(pr.y, pz.y, gi.y, gh.y, hi16(h1cp));
            hn1p = pkrtz(h0, h1);
        }
        if (w == 0) {
            float v = (la < 50) ? fdot2u(rawc, hn1p, 0.f) : 0.f;
            v = wsum(v);
            if (la == 0) S.sv[1][t] = v;
            if (la < 50) S.cache_t[1][la][t] = hn1p;
        }
        if (tid >= 300 && tid < 400) {
            // c-part: 4 chains off LDS cpkq
            float p0a=fb0, p0b=0.f, p1a=fb0, p1b=0.f;
            #pragma unroll
            for (int k = 0; k < 50; k += 2) {
                uint2 v0 = *(const uint2*)&S.cpkq[0][k];
                uint2 v1 = *(const uint2*)&S.cpkq[1][k];
                p0a = fdot2u(wA[k],   v0.x, p0a);
                p1a = fdot2u(wA[k],   v1.x, p1a);
                p0b = fdot2u(wA[k+1], v0.y, p0b);
                p1b = fdot2u(wA[k+1], v1.y, p1b);
            }
            // hn-part: 4 chains off readlane broadcast
            float q0a=0.f, q0b=0.f, q1a=0.f, q1b=0.f;
            #pragma unroll
            for (int k = 0; k < 50; k += 2) {
                uint32_t ha=rlane(hn0p,k), hb=rlane(hn0p,k+1);
                uint32_t hc=rlane(hn1p,k), hd=rlane(hn1p,k+1);
                q0a = fdot2u(wB[k],   ha, q0a);
                q1a = fdot2u(wB[k],   hc, q1a);
                q0b = fdot2u(wB[k+1], hb, q0b);
                q1b = fdot2u(wB[k+1], hd, q1b);
            }
            S.hmix0[tid-300] = (p0a+p0b) + (q0a+q0b);
            S.hmix1[tid-300] = (p1a+p1b) + (q1a+q1b);
        }
        __syncthreads();
    }
    // epilogue: readout for t = 63
    if (w == 7) {
        float v = (la < 50) ? fdot2u(rowp, hn1p, 0.f) : 0.f;
        v = wsum(v);
        if (la == 0) p_out[br*8192 + b*64 + 63] = v;
    }
}

// ---------------- final: pair partials across branches, sigmoid ----------------
__global__ void fin_out(const uint32_t* __restrict__ ws, const float* __restrict__ outb,
                        float* __restrict__ out) {
    int i = blockIdx.x*blockDim.x + threadIdx.x;
    if (i >= NB*T64) return;
    int b = i >> 6, t = i & 63;
    const float* p = (const float*)(ws + OFF_P);
    int t2 = t + DLAG; if (t2 > T64-1) t2 = T64-1;
    float logit = p[0*8192 + b*64 + t] + p[1*8192 + b*64 + t2] + outb[0];
    out[i] = 1.f/(1.f+__expf(-logit));
}

extern "C" void kernel_launch(void* const* d_in, const int* in_sizes, int n_in,
                              void* d_out, int out_size, void* d_ws, size_t ws_size,
                              hipStream_t stream) {
    const float* recv   = (const float*)d_in[0];
    const float* w1ih0  = (const float*)d_in[1];
    const float* w1hh0  = (const float*)d_in[2];
    const float* w1bih0 = (const float*)d_in[3];
    const float* w1bhh0 = (const float*)d_in[4];
    const float* w1ih1  = (const float*)d_in[5];
    const float* w1hh1  = (const float*)d_in[6];
    const float* w1bih1 = (const float*)d_in[7];
    const float* w1bhh1 = (const float*)d_in[8];
    const float* w2ih0  = (const float*)d_in[9];
    const float* w2hh0  = (const float*)d_in[10];
    const float* w2bih0 = (const float*)d_in[11];
    const float* w2bhh0 = (const float*)d_in[12];
    const float* w2ih1  = (const float*)d_in[13];
    const float* w2hh1  = (const float*)d_in[14];
    const float* w2bih1 = (const float*)d_in[15];
    const float* w2bhh1 = (const float*)d_in[16];
    const float* attw   = (const float*)d_in[17];
    const float* ctxw   = (const float*)d_in[19];
    const float* ctxb   = (const float*)d_in[20];
    const float* outw   = (const float*)d_in[21];
    const float* outb   = (const float*)d_in[22];
    uint32_t* ws = (uint32_t*)d_ws;
    float* out = (float*)d_out;

    prep_pack<<<(100150 + 255)/256, 256, 0, stream>>>(
        w1hh0, w2hh0, w1ih1, w2ih1, w1hh1, w2hh1, attw, ctxw, outw, ws);

    gru_seq<<<256, 512, 0, stream>>>(
        recv,
        w1ih0, w1bih0, w1bhh0, w1bih1, w1bhh1,
        w2ih0, w2bih0, w2bhh0, w2bih1, w2bhh1,
        ctxb, ws);

    fin_out<<<(NB*T64 + 255)/256, 256, 0, stream>>>(ws, outb, out);
}

// Round 10
// 226.983 us; speedup vs baseline: 1.2608x; 1.0599x over previous
//
#include <hip/hip_runtime.h>
#include <stdint.h>

#define H100 100
#define T64  64
#define NB   128
#define DLAG 10

// ---- workspace layout (uint32 offsets) ----
#define OFF_HH0 0          // [2][300][50] hh0 row-pair-packed
#define OFF_IH1 30000      // [2][300][50]
#define OFF_HH1 60000      // [2][300][50]
#define OFF_CTX 90000      // [100][100]  ctx row-pair-packed (o-major)
#define OFF_AWC 100000     // [50] attn_w[0][100:200] pairs
#define OFF_OW  100050     // [2][50] out_w halves pairs
#define OFF_P   100152     // float [2][128][64] partial readouts

typedef _Float16 half2_t __attribute__((ext_vector_type(2)));
typedef __fp16   pk16x2  __attribute__((ext_vector_type(2)));

__device__ __forceinline__ float fdot2u(uint32_t a, uint32_t b, float c) {
#if __has_builtin(__builtin_amdgcn_fdot2)
    return __builtin_amdgcn_fdot2(__builtin_bit_cast(half2_t, a),
                                  __builtin_bit_cast(half2_t, b), c, false);
#else
    half2_t ha = __builtin_bit_cast(half2_t, a), hb = __builtin_bit_cast(half2_t, b);
    return c + (float)ha[0]*(float)hb[0] + (float)ha[1]*(float)hb[1];
#endif
}
__device__ __forceinline__ uint32_t pkrtz(float a, float b) {
    pk16x2 h = __builtin_amdgcn_cvt_pkrtz(a, b);
    return __builtin_bit_cast(uint32_t, h);
}
__device__ __forceinline__ uint32_t pk_rn(float a, float b) {
    half2_t h; h[0] = (_Float16)a; h[1] = (_Float16)b;
    return __builtin_bit_cast(uint32_t, h);
}
__device__ __forceinline__ float lo16(uint32_t u){ return (float)__builtin_bit_cast(half2_t,u)[0]; }
__device__ __forceinline__ float hi16(uint32_t u){ return (float)__builtin_bit_cast(half2_t,u)[1]; }
__device__ __forceinline__ float sigm(float x){ return 1.f/(1.f+__expf(-x)); }
__device__ __forceinline__ float tanhfast(float x){ return 1.f - 2.f/(1.f+__expf(2.f*x)); }
__device__ __forceinline__ float gru_el(float pr, float pz, float gin, float ghn, float hp) {
    float r = sigm(pr), z = sigm(pz);
    float n = tanhfast(gin + r*ghn);
    return (1.f - z)*n + z*hp;
}
__device__ __forceinline__ float wsum(float v){
    #pragma unroll
    for (int off = 32; off; off >>= 1) v += __shfl_xor(v, off);
    return v;
}
__device__ __forceinline__ float wmax(float v){
    #pragma unroll
    for (int off = 32; off; off >>= 1) v = fmaxf(v, __shfl_xor(v, off));
    return v;
}

struct SMem {
    alignas(16) uint32_t cache_t[2][50][66];  // transposed hidden cache, pad 66
    alignas(16) float grz1[200];
    alignas(16) float gin1[104];
    alignas(16) float ghn1[104];
    alignas(16) float grz2[200];
    alignas(16) float gin2[104];
    alignas(16) float ghn2[104];
    alignas(16) float sv[2][64];
    alignas(16) float atile[2][64];
    alignas(16) uint32_t cpkq[2][52];   // attention context, f16 pairs (normalized)
    alignas(16) uint32_t h0c[52];       // carry hidden, packed pairs
    alignas(16) uint32_t h1c[52];
    alignas(16) uint32_t hn0[52];       // raw GRU outputs, packed pairs
    alignas(16) uint32_t hn1[52];
    alignas(16) float x[192];
};

// ---------------- prep: pack weights to f16 pairs ----------------
__global__ void prep_pack(const float* __restrict__ w1hh0, const float* __restrict__ w2hh0,
                          const float* __restrict__ w1ih1, const float* __restrict__ w2ih1,
                          const float* __restrict__ w1hh1, const float* __restrict__ w2hh1,
                          const float* __restrict__ attw,  const float* __restrict__ ctxw,
                          const float* __restrict__ outw,  uint32_t* __restrict__ ws) {
    int g = blockIdx.x*blockDim.x + threadIdx.x;
    if (g < 30000) {
        int br = g/15000, idx = g%15000;
        int j = idx/50, kp = idx%50;
        const float* w = br ? w2hh0 : w1hh0;
        ws[OFF_HH0 + g] = pk_rn(w[j*H100+2*kp], w[j*H100+2*kp+1]);
    } else if (g < 60000) {
        int t2 = g-30000; int br = t2/15000, idx = t2%15000;
        int j = idx/50, kp = idx%50;
        const float* w = br ? w2ih1 : w1ih1;
        ws[OFF_IH1 + t2] = pk_rn(w[j*H100+2*kp], w[j*H100+2*kp+1]);
    } else if (g < 90000) {
        int t2 = g-60000; int br = t2/15000, idx = t2%15000;
        int j = idx/50, kp = idx%50;
        const float* w = br ? w2hh1 : w1hh1;
        ws[OFF_HH1 + t2] = pk_rn(w[j*H100+2*kp], w[j*H100+2*kp+1]);
    } else if (g < 100000) {
        int idx = g-90000; int o = idx/100, kp = idx%100;
        ws[OFF_CTX + idx] = pk_rn(ctxw[o*200+2*kp], ctxw[o*200+2*kp+1]);
    } else if (g < 100050) {
        int i2 = g-100000;
        ws[OFF_AWC + i2] = pk_rn(attw[100+2*i2], attw[101+2*i2]);
    } else if (g < 100150) {
        int t2 = g-100050; int br = t2/50, i2 = t2%50;
        ws[OFF_OW + t2] = pk_rn(outw[br*H100+2*i2], outw[br*H100+2*i2+1]);
    }
}

// ---------------- main: one block per (branch, batch) chain ----------------
// 5 single-owner phases per step; h operands via LDS broadcast b128 reads
// (conflict-free same-address), no readlane, no redundant combines.
__global__ __launch_bounds__(512, 1)
void gru_seq(const float* __restrict__ recv,
             const float* __restrict__ ih0_1, const float* __restrict__ bih0_1,
             const float* __restrict__ bhh0_1, const float* __restrict__ bih1_1,
             const float* __restrict__ bhh1_1,
             const float* __restrict__ ih0_2, const float* __restrict__ bih0_2,
             const float* __restrict__ bhh0_2, const float* __restrict__ bih1_2,
             const float* __restrict__ bhh1_2,
             const float* __restrict__ ctxb,
             uint32_t* __restrict__ ws) {
    __shared__ SMem S;
    const int tid = threadIdx.x;
    const int w   = tid >> 6;
    const int la  = tid & 63;
    const int br  = blockIdx.x >> 7;
    const int b   = blockIdx.x & 127;

    const float* ih0 = br ? ih0_2  : ih0_1;
    const float* bi0 = br ? bih0_2 : bih0_1;
    const float* bh0 = br ? bhh0_2 : bhh0_1;
    const float* bi1 = br ? bih1_2 : bih1_1;
    const float* bh1 = br ? bhh1_2 : bhh1_1;

    // staging + init
    for (int i = tid; i < 192; i += 512) S.x[i] = recv[b*192 + i];
    for (int i = tid; i < 2*50*66; i += 512) ((uint32_t*)S.cache_t)[i] = 0u;
    if (tid < 128) S.sv[tid>>6][tid&63] = 0.f;
    if (tid < 104) { S.cpkq[0][tid>>1] = 0u; S.cpkq[1][tid>>1] = 0u; }  // covers 0..51 twice, harmless
    if (tid >= 128 && tid < 180) { int i2 = tid-128; S.h0c[i2]=0u; S.h1c[i2]=0u; S.hn0[i2]=0u; S.hn1[i2]=0u; }

    // role-overlaid register file:
    //  gates (tid<300): wreg[0:50)=hh0row [50:100)=hh1row [100:150)=ih1row
    //  ctx   (300-399): wreg[0:100)=ctx row
    uint32_t wreg[150];
    float fb0=0.f, fb1=0.f, fb2=0.f, fb3=0.f;
    float rix0=0.f, rix1=0.f, rix2=0.f;
    if (tid < 300) {
        const uint32_t* p0 = ws + OFF_HH0 + br*15000 + tid*50;
        const uint32_t* p1 = ws + OFF_HH1 + br*15000 + tid*50;
        const uint32_t* p2 = ws + OFF_IH1 + br*15000 + tid*50;
        #pragma unroll
        for (int k = 0; k < 50; ++k) { wreg[k] = p0[k]; wreg[50+k] = p1[k]; wreg[100+k] = p2[k]; }
        fb0 = bi0[tid]; fb1 = bh0[tid]; fb2 = bi1[tid]; fb3 = bh1[tid];
        rix0 = ih0[tid*3]; rix1 = ih0[tid*3+1]; rix2 = ih0[tid*3+2];
    } else if (tid < 400) {
        const int o = tid - 300;
        const uint32_t* pc = ws + OFF_CTX + o*100;
        #pragma unroll
        for (int k = 0; k < 100; ++k) wreg[k] = pc[k];
        fb0 = ctxb[o];
    }
    uint32_t rawc = 0u, rowp = 0u;
    if ((w == 5 || w == 6) && la < 50) rawc = ws[OFF_AWC + la];
    if (w == 7 && la < 50) rowp = ws[OFF_OW + br*50 + la];
    float* p_out = (float*)(ws + OFF_P);

    float gh1save = 0.f;
    __syncthreads();

    for (int t = 0; t < T64; ++t) {
        // ===== P1: gates0 + gh1 (tid<300, LDS-bcast h) | attn l=w-5 (w5,w6) =====
        if (tid < 300) {
            float x0 = S.x[3*t], x1 = S.x[3*t+1], x2 = S.x[3*t+2];
            float accI = fb0 + rix0*x0 + rix1*x1 + rix2*x2;
            float a0=0.f,a1=0.f,a2=0.f,a3=0.f, b0=0.f,b1=0.f,b2=0.f,b3=0.f;
            #pragma unroll
            for (int i = 0; i < 12; ++i) {
                uint4 h0 = *(const uint4*)&S.h0c[4*i];
                uint4 h1 = *(const uint4*)&S.h1c[4*i];
                a0 = fdot2u(wreg[4*i],    h0.x, a0);
                b0 = fdot2u(wreg[50+4*i], h1.x, b0);
                a1 = fdot2u(wreg[4*i+1],    h0.y, a1);
                b1 = fdot2u(wreg[50+4*i+1], h1.y, b1);
                a2 = fdot2u(wreg[4*i+2],    h0.z, a2);
                b2 = fdot2u(wreg[50+4*i+2], h1.z, b2);
                a3 = fdot2u(wreg[4*i+3],    h0.w, a3);
                b3 = fdot2u(wreg[50+4*i+3], h1.w, b3);
            }
            {
                uint2 h0t = *(const uint2*)&S.h0c[48];
                uint2 h1t = *(const uint2*)&S.h1c[48];
                a0 = fdot2u(wreg[48],    h0t.x, a0);
                b0 = fdot2u(wreg[98],    h1t.x, b0);
                a1 = fdot2u(wreg[49],    h0t.y, a1);
                b1 = fdot2u(wreg[99],    h1t.y, b1);
            }
            float acc0 = fb1 + ((a0+a1)+(a2+a3));
            gh1save    = fb3 + ((b0+b1)+(b2+b3));
            if (tid < 200) S.grz1[tid] = accI + acc0;
            else { S.gin1[tid-200] = accI; S.ghn1[tid-200] = acc0; }
        } else if (w == 5 || w == 6) {
            const int l = w - 5;
            const int m = (t > 1) ? t : 1;
            float sval = S.sv[l][la];
            float sv2  = (la < m) ? sval : -3e38f;
            float mx   = wmax(sv2);
            float p    = (la < m) ? __expf(sv2 - mx) : 0.f;
            float ssum = wsum(p);
            S.atile[l][la] = p;
            if (la < 50) {
                float c0 = 0.f, c1 = 0.f;
                const uint32_t* crow = &S.cache_t[l][la][0];
                const int np = (m + 1) >> 1;
                // chunked x8 pairs: <=4 latency waits; tail pairs read zeros
                for (int tb = 0; tb < np; tb += 8) {
                    float2 ap[8]; uint2 cp[8];
                    #pragma unroll
                    for (int j = 0; j < 8; ++j) {
                        ap[j] = *(const float2*)&S.atile[l][2*(tb+j)];
                        cp[j] = *(const uint2*)&crow[2*(tb+j)];
                    }
                    #pragma unroll
                    for (int j = 0; j < 8; ++j) {
                        c0 += ap[j].x*lo16(cp[j].x) + ap[j].y*lo16(cp[j].y);
                        c1 += ap[j].x*hi16(cp[j].x) + ap[j].y*hi16(cp[j].y);
                    }
                }
                float inv = 1.f/ssum;
                S.cpkq[l][la] = pkrtz(c0*inv, c1*inv);
            }
        }
        __syncthreads();  // B1
        // ===== P2: hn0-combine (w5) ; readout t-1 (w7) =====
        if (w == 5) {
            uint32_t hn0p = 0u;
            if (la < 50) {
                float2 pr = *(const float2*)&S.grz1[2*la];
                float2 pz = *(const float2*)&S.grz1[100+2*la];
                float2 gi = *(const float2*)&S.gin1[2*la];
                float2 gh = *(const float2*)&S.ghn1[2*la];
                uint32_t hp = S.h0c[la];
                float h0 = gru_el(pr.x, pz.x, gi.x, gh.x, lo16(hp));
                float h1 = gru_el(pr.y, pz.y, gi.y, gh.y, hi16(hp));
                hn0p = pkrtz(h0, h1);
                S.hn0[la] = hn0p;
                S.cache_t[0][la][t] = hn0p;
            }
            float v = (la < 50) ? fdot2u(rawc, hn0p, 0.f) : 0.f;
            v = wsum(v);
            if (la == 0) S.sv[0][t] = v;
        } else if (w == 7 && t > 0) {
            float v = (la < 50) ? fdot2u(rowp, S.hn1[la], 0.f) : 0.f;
            v = wsum(v);
            if (la == 0) p_out[br*8192 + b*64 + (t-1)] = v;
        }
        __syncthreads();  // B2
        // ===== P3: gi1 (tid<300, LDS-bcast hn0) =====
        if (tid < 300) {
            float g0=0.f,g1=0.f,g2=0.f,g3=0.f;
            #pragma unroll
            for (int i = 0; i < 12; ++i) {
                uint4 h = *(const uint4*)&S.hn0[4*i];
                g0 = fdot2u(wreg[100+4*i],   h.x, g0);
                g1 = fdot2u(wreg[100+4*i+1], h.y, g1);
                g2 = fdot2u(wreg[100+4*i+2], h.z, g2);
                g3 = fdot2u(wreg[100+4*i+3], h.w, g3);
            }
            {
                uint2 ht = *(const uint2*)&S.hn0[48];
                g0 = fdot2u(wreg[148], ht.x, g0);
                g1 = fdot2u(wreg[149], ht.y, g1);
            }
            float gi1 = fb2 + ((g0+g1)+(g2+g3));
            if (tid < 200) S.grz2[tid] = gi1 + gh1save;
            else { S.gin2[tid-200] = gi1; S.ghn2[tid-200] = gh1save; }
        }
        __syncthreads();  // B3
        // ===== P4: hn1-combine (w6) =====
        if (w == 6) {
            uint32_t hn1p = 0u;
            if (la < 50) {
                float2 pr = *(const float2*)&S.grz2[2*la];
                float2 pz = *(const float2*)&S.grz2[100+2*la];
                float2 gi = *(const float2*)&S.gin2[2*la];
                float2 gh = *(const float2*)&S.ghn2[2*la];
                uint32_t hp = S.h1c[la];
                float h0 = gru_el(pr.x, pz.x, gi.x, gh.x, lo16(hp));
                float h1 = gru_el(pr.y, pz.y, gi.y, gh.y, hi16(hp));
                hn1p = pkrtz(h0, h1);
                S.hn1[la] = hn1p;
                S.cache_t[1][la][t] = hn1p;
            }
            float v = (la < 50) ? fdot2u(rawc, hn1p, 0.f) : 0.f;
            v = wsum(v);
            if (la == 0) S.sv[1][t] = v;
        }
        __syncthreads();  // B4
        // ===== P5: ctx full rows (tid 300-399) -> pair-packed carry ; t==0 raw copy (w7) =====
        if (tid >= 300 && tid < 400) {
            const int o = tid - 300;
            float p0a=fb0, p0b=0.f, q0a=0.f, q0b=0.f;
            float p1a=fb0, p1b=0.f, q1a=0.f, q1b=0.f;
            #pragma unroll
            for (int i = 0; i < 12; ++i) {
                uint4 c0 = *(const uint4*)&S.cpkq[0][4*i];
                uint4 c1 = *(const uint4*)&S.cpkq[1][4*i];
                uint4 h0 = *(const uint4*)&S.hn0[4*i];
                uint4 h1 = *(const uint4*)&S.hn1[4*i];
                p0a = fdot2u(wreg[4*i],   c0.x, p0a);
                p1a = fdot2u(wreg[4*i],   c1.x, p1a);
                q0a = fdot2u(wreg[50+4*i],   h0.x, q0a);
                q1a = fdot2u(wreg[50+4*i],   h1.x, q1a);
                p0b = fdot2u(wreg[4*i+1], c0.y, p0b);
                p1b = fdot2u(wreg[4*i+1], c1.y, p1b);
                q0b = fdot2u(wreg[50+4*i+1], h0.y, q0b);
                q1b = fdot2u(wreg[50+4*i+1], h1.y, q1b);
                p0a = fdot2u(wreg[4*i+2], c0.z, p0a);
                p1a = fdot2u(wreg[4*i+2], c1.z, p1a);
                q0a = fdot2u(wreg[50+4*i+2], h0.z, q0a);
                q1a = fdot2u(wreg[50+4*i+2], h1.z, q1a);
                p0b = fdot2u(wreg[4*i+3], c0.w, p0b);
                p1b = fdot2u(wreg[4*i+3], c1.w, p1b);
                q0b = fdot2u(wreg[50+4*i+3], h0.w, q0b);
                q1b = fdot2u(wreg[50+4*i+3], h1.w, q1b);
            }
            {
                uint2 c0 = *(const uint2*)&S.cpkq[0][48];
                uint2 c1 = *(const uint2*)&S.cpkq[1][48];
                uint2 h0 = *(const uint2*)&S.hn0[48];
                uint2 h1 = *(const uint2*)&S.hn1[48];
                p0a = fdot2u(wreg[48], c0.x, p0a);
                p1a = fdot2u(wreg[48], c1.x, p1a);
                q0a = fdot2u(wreg[98], h0.x, q0a);
                q1a = fdot2u(wreg[98], h1.x, q1a);
                p0b = fdot2u(wreg[49], c0.y, p0b);
                p1b = fdot2u(wreg[49], c1.y, p1b);
                q0b = fdot2u(wreg[99], h0.y, q0b);
                q1b = fdot2u(wreg[99], h1.y, q1b);
            }
            float m0 = (p0a+p0b) + (q0a+q0b);
            float m1 = (p1a+p1b) + (q1a+q1b);
            // pair-pack via intra-wave shfl (pairs never straddle a wave: base 300 even)
            float n0 = __shfl_down(m0, 1);
            float n1 = __shfl_down(m1, 1);
            if (t > 0 && !(o & 1)) {
                S.h0c[o>>1] = pkrtz(m0, n0);
                S.h1c[o>>1] = pkrtz(m1, n1);
            }
        } else if (w == 7 && t == 0) {
            if (la < 50) { S.h0c[la] = S.hn0[la]; S.h1c[la] = S.hn1[la]; }
        }
        __syncthreads();  // B5
    }
    // epilogue: readout for t = 63
    if (w == 7) {
        float v = (la < 50) ? fdot2u(rowp, S.hn1[la], 0.f) : 0.f;
        v = wsum(v);
        if (la == 0) p_out[br*8192 + b*64 + 63] = v;
    }
}

// ---------------- final: pair partials across branches, sigmoid ----------------
__global__ void fin_out(const uint32_t* __restrict__ ws, const float* __restrict__ outb,
                        float* __restrict__ out) {
    int i = blockIdx.x*blockDim.x + threadIdx.x;
    if (i >= NB*T64) return;
    int b = i >> 6, t = i & 63;
    const float* p = (const float*)(ws + OFF_P);
    int t2 = t + DLAG; if (t2 > T64-1) t2 = T64-1;
    float logit = p[0*8192 + b*64 + t] + p[1*8192 + b*64 + t2] + outb[0];
    out[i] = 1.f/(1.f+__expf(-logit));
}

extern "C" void kernel_launch(void* const* d_in, const int* in_sizes, int n_in,
                              void* d_out, int out_size, void* d_ws, size_t ws_size,
                              hipStream_t stream) {
    const float* recv   = (const float*)d_in[0];
    const float* w1ih0  = (const float*)d_in[1];
    const float* w1hh0  = (const float*)d_in[2];
    const float* w1bih0 = (const float*)d_in[3];
    const float* w1bhh0 = (const float*)d_in[4];
    const float* w1ih1  = (const float*)d_in[5];
    const float* w1hh1  = (const float*)d_in[6];
    const float* w1bih1 = (const float*)d_in[7];
    const float* w1bhh1 = (const float*)d_in[8];
    const float* w2ih0  = (const float*)d_in[9];
    const float* w2hh0  = (const float*)d_in[10];
    const float* w2bih0 = (const float*)d_in[11];
    const float* w2bhh0 = (const float*)d_in[12];
    const float* w2ih1  = (const float*)d_in[13];
    const float* w2hh1  = (const float*)d_in[14];
    const float* w2bih1 = (const float*)d_in[15];
    const float* w2bhh1 = (const float*)d_in[16];
    const float* attw   = (const float*)d_in[17];
    const float* ctxw   = (const float*)d_in[19];
    const float* ctxb   = (const float*)d_in[20];
    const float* outw   = (const float*)d_in[21];
    const float* outb   = (const float*)d_in[22];
    uint32_t* ws = (uint32_t*)d_ws;
    float* out = (float*)d_out;

    prep_pack<<<(100150 + 255)/256, 256, 0, stream>>>(
        w1hh0, w2hh0, w1ih1, w2ih1, w1hh1, w2hh1, attw, ctxw, outw, ws);

    gru_seq<<<256, 512, 0, stream>>>(
        recv,
        w1ih0, w1bih0, w1bhh0, w1bih1, w1bhh1,
        w2ih0, w2bih0, w2bhh0, w2bih1, w2bhh1,
        ctxb, ws);

    fin_out<<<(NB*T64 + 255)/256, 256, 0, stream>>>(ws, outb, out);
}